// Round 2
// baseline (286.272 us; speedup 1.0000x reference)
//
#include <hip/hip_runtime.h>
#include <math.h>

#define NG 16
#define DIM 64
#define LOG_2PI 1.8378770664093453f
#define RPW 4                      // rows per wave
#define WPB 4                      // waves per block (256 threads)
#define ROWS_PER_BLOCK (RPW * WPB) // 16

// One WAVE per row, 2048 blocks (dispatch-rate safe), PERFECT coalescing:
// load k (k=0..3) reads float4 index (lane + 64k) of the 256-float4 row --
// each instruction is a contiguous 1KB wave access (8 x 128B lines), vs the
// previous version's stride-64B gather (64 lines/instr, TA-throughput-bound).
//
// Layout algebra: float4 f of a row -> gaussian f>>4, dim-chunk f&15.
// f = lane + 64k  =>  gaussian = (lane>>4) + 4k,  chunk = lane&15 (same for
// all k!). So each lane needs exactly ONE target float4 T4[lane&15], and
// holds one float4 of gaussians {G, G+4, G+8, G+12} where G = lane>>4.
// All 13 loads of a row are independent -> one vmcnt wait per row.
//
// Reduction: xor-butterfly 1,2,4,8 within the 16-lane group sums the 16
// chunks of each of the group's 4 gaussians; each lane then does a local
// 4-wide logsumexp over its 4 gaussians; groups hold DISJOINT gaussian sets,
// merged with two LSE-merge steps (xor 16, xor 32). No LDS, no barriers.
__global__ __launch_bounds__(256) void gmm_loss_kernel(
    const float* __restrict__ means,
    const float* __restrict__ covs,
    const float* __restrict__ weights,
    const float* __restrict__ targets,
    float* __restrict__ out, int B)
{
    const int lane = threadIdx.x & 63;
    const int wave = threadIdx.x >> 6;
    const int G = lane >> 4;     // lane group = base gaussian
    const int c = lane & 15;     // dim-chunk (target float4 index)

    int b = blockIdx.x * ROWS_PER_BLOCK + wave * RPW;

    #pragma unroll 1
    for (int r = 0; r < RPW; ++r, ++b) {
        if (b >= B) break;

        const float4* M4 = (const float4*)(means + (size_t)b * (NG * DIM));
        const float4* V4 = (const float4*)(covs  + (size_t)b * (NG * DIM));
        const float4* T4 = (const float4*)(targets + (size_t)b * DIM);
        const float*  W  = weights + (size_t)b * NG;

        // 13 independent loads, all issued before any use.
        // m/v: contiguous 1KB per instruction. t: 16 distinct float4s in a
        // 256B row (broadcast x4). w: 4 scalars in one 64B line (broadcast).
        const float4 m0 = M4[lane];       const float4 v0 = V4[lane];
        const float4 m1 = M4[lane + 64];  const float4 v1 = V4[lane + 64];
        const float4 m2 = M4[lane + 128]; const float4 v2 = V4[lane + 128];
        const float4 m3 = M4[lane + 192]; const float4 v3 = V4[lane + 192];
        const float4 t  = T4[c];
        const float w0 = W[G];      const float w1 = W[G + 4];
        const float w2 = W[G + 8];  const float w3 = W[G + 12];

        // per-float4 partial: quad-form terms + log of the 4-var product
        // (product in [0.0625, 5.06] -> exact-safe, same numerics as the
        // previously verified kernel)
        float dx, p0, p1, p2, p3;
        dx = t.x - m0.x; p0  = dx * dx * __builtin_amdgcn_rcpf(v0.x);
        dx = t.y - m0.y; p0 += dx * dx * __builtin_amdgcn_rcpf(v0.y);
        dx = t.z - m0.z; p0 += dx * dx * __builtin_amdgcn_rcpf(v0.z);
        dx = t.w - m0.w; p0 += dx * dx * __builtin_amdgcn_rcpf(v0.w);
        p0 += __logf(v0.x * v0.y * v0.z * v0.w);

        dx = t.x - m1.x; p1  = dx * dx * __builtin_amdgcn_rcpf(v1.x);
        dx = t.y - m1.y; p1 += dx * dx * __builtin_amdgcn_rcpf(v1.y);
        dx = t.z - m1.z; p1 += dx * dx * __builtin_amdgcn_rcpf(v1.z);
        dx = t.w - m1.w; p1 += dx * dx * __builtin_amdgcn_rcpf(v1.w);
        p1 += __logf(v1.x * v1.y * v1.z * v1.w);

        dx = t.x - m2.x; p2  = dx * dx * __builtin_amdgcn_rcpf(v2.x);
        dx = t.y - m2.y; p2 += dx * dx * __builtin_amdgcn_rcpf(v2.y);
        dx = t.z - m2.z; p2 += dx * dx * __builtin_amdgcn_rcpf(v2.z);
        dx = t.w - m2.w; p2 += dx * dx * __builtin_amdgcn_rcpf(v2.w);
        p2 += __logf(v2.x * v2.y * v2.z * v2.w);

        dx = t.x - m3.x; p3  = dx * dx * __builtin_amdgcn_rcpf(v3.x);
        dx = t.y - m3.y; p3 += dx * dx * __builtin_amdgcn_rcpf(v3.y);
        dx = t.z - m3.z; p3 += dx * dx * __builtin_amdgcn_rcpf(v3.z);
        dx = t.w - m3.w; p3 += dx * dx * __builtin_amdgcn_rcpf(v3.w);
        p3 += __logf(v3.x * v3.y * v3.z * v3.w);

        // sum the 16 chunks of each gaussian within the 16-lane group
        p0 += __shfl_xor(p0, 1); p1 += __shfl_xor(p1, 1);
        p2 += __shfl_xor(p2, 1); p3 += __shfl_xor(p3, 1);
        p0 += __shfl_xor(p0, 2); p1 += __shfl_xor(p1, 2);
        p2 += __shfl_xor(p2, 2); p3 += __shfl_xor(p3, 2);
        p0 += __shfl_xor(p0, 4); p1 += __shfl_xor(p1, 4);
        p2 += __shfl_xor(p2, 4); p3 += __shfl_xor(p3, 4);
        p0 += __shfl_xor(p0, 8); p1 += __shfl_xor(p1, 8);
        p2 += __shfl_xor(p2, 8); p3 += __shfl_xor(p3, 8);

        // per-gaussian weighted log-prob
        const float base = -0.5f * (DIM * LOG_2PI);
        float lw0 = base - 0.5f * p0;
        float lw1 = base - 0.5f * p1;
        float lw2 = base - 0.5f * p2;
        float lw3 = base - 0.5f * p3;
        lw0 = fminf(fmaxf(lw0, -100.0f), 0.0f) + __logf(w0);
        lw1 = fminf(fmaxf(lw1, -100.0f), 0.0f) + __logf(w1);
        lw2 = fminf(fmaxf(lw2, -100.0f), 0.0f) + __logf(w2);
        lw3 = fminf(fmaxf(lw3, -100.0f), 0.0f) + __logf(w3);

        // local 4-wide logsumexp over this lane's 4 gaussians
        float M = fmaxf(fmaxf(lw0, lw1), fmaxf(lw2, lw3));
        float s = __expf(lw0 - M) + __expf(lw1 - M) +
                  __expf(lw2 - M) + __expf(lw3 - M);

        // merge across the 4 groups (disjoint gaussian sets): xor 16, xor 32
        {
            const float Mo = __shfl_xor(M, 16);
            const float so = __shfl_xor(s, 16);
            const float Mn = fmaxf(M, Mo);
            s = s * __expf(M - Mn) + so * __expf(Mo - Mn);
            M = Mn;
        }
        {
            const float Mo = __shfl_xor(M, 32);
            const float so = __shfl_xor(s, 32);
            const float Mn = fmaxf(M, Mo);
            s = s * __expf(M - Mn) + so * __expf(Mo - Mn);
            M = Mn;
        }

        if (lane == 0) out[b] = -(M + __logf(s));
    }
}

extern "C" void kernel_launch(void* const* d_in, const int* in_sizes, int n_in,
                              void* d_out, int out_size, void* d_ws, size_t ws_size,
                              hipStream_t stream) {
    const float* means   = (const float*)d_in[0];
    const float* covs    = (const float*)d_in[1];
    const float* weights = (const float*)d_in[2];
    const float* targets = (const float*)d_in[3];
    float* out = (float*)d_out;

    const int B = in_sizes[0] / (NG * DIM);                      // 32768
    const int grid = (B + ROWS_PER_BLOCK - 1) / ROWS_PER_BLOCK;  // 2048
    gmm_loss_kernel<<<grid, 256, 0, stream>>>(means, covs, weights, targets, out, B);
}

// Round 3
// 264.587 us; speedup vs baseline: 1.0820x; 1.0820x over previous
//
#include <hip/hip_runtime.h>
#include <math.h>

#define NG 16
#define DIM 64
#define LOG_2PI 1.8378770664093453f
#define RPW 4                      // rows per wave
#define WPB 4                      // waves per block (256 threads)
#define ROWS_PER_BLOCK (RPW * WPB) // 16

typedef float f32x4 __attribute__((ext_vector_type(4)));

// Round-3 theory: rounds 0-2 all sat at ~100us / ~2.6 TB/s effective because
// (a) the compiler sank the "independent" loads to their uses (VGPR_Count=32
// proved <=2 loads were ever in flight per wave -> latency-bound), and
// (b) the 266MB single-use stream thrashes the 256MB LLC.
// Fix: register DOUBLE-BUFFERED row pipeline -- issue row r+1's 8 m/v loads
// into the other named buffer BEFORE computing row r (compiler must keep them
// co-resident; expect ~96-128 VGPRs), and use NONTEMPORAL loads on the m/v
// streams so they stop evicting the LLC. 8KB in flight per wave during every
// compute phase, ~16 waves/CU -> concurrency no longer the limiter.
//
// Mapping (verified in round 2, absmax=0): float4 f = lane + 64k of a row ->
// gaussian (lane>>4)+4k, dim-chunk lane&15 (same for all k). Butterfly 1/2/4/8
// sums chunks; local 4-wide LSE; merge disjoint groups via xor 16/32.

#define NT(p) __builtin_nontemporal_load(p)

__global__ __launch_bounds__(256) void gmm_loss_kernel(
    const float* __restrict__ means,
    const float* __restrict__ covs,
    const float* __restrict__ weights,
    const float* __restrict__ targets,
    float* __restrict__ out, int B)
{
    const int lane = threadIdx.x & 63;
    const int wave = threadIdx.x >> 6;
    const int G = lane >> 4;     // lane group = base gaussian
    const int c = lane & 15;     // dim-chunk (target float4 index)

    const int b0 = blockIdx.x * ROWS_PER_BLOCK + wave * RPW;

    // ---- issue row (bb)'s 8 big loads into buffer S (nontemporal) ----
#define ISSUE(S, bb) {                                                        \
        const int rb = (bb) < B ? (bb) : (B - 1);                             \
        const f32x4* Mp = (const f32x4*)(means + (size_t)rb * (NG * DIM));    \
        const f32x4* Vp = (const f32x4*)(covs  + (size_t)rb * (NG * DIM));    \
        m0##S = NT(Mp + lane);       v0##S = NT(Vp + lane);                   \
        m1##S = NT(Mp + lane + 64);  v1##S = NT(Vp + lane + 64);              \
        m2##S = NT(Mp + lane + 128); v2##S = NT(Vp + lane + 128);             \
        m3##S = NT(Mp + lane + 192); v3##S = NT(Vp + lane + 192);             \
    }

    // ---- consume buffer S for row (bb): quad+logdet, reduce, LSE, store ----
#define COMPUTE(S, bb) {                                                      \
        const int rb = (bb) < B ? (bb) : (B - 1);                             \
        const f32x4 t = ((const f32x4*)(targets + (size_t)rb * DIM))[c];      \
        const float* W = weights + (size_t)rb * NG;                           \
        const float w0 = W[G];     const float w1 = W[G + 4];                 \
        const float w2 = W[G + 8]; const float w3 = W[G + 12];                \
        float dx, p0, p1, p2, p3;                                             \
        dx = t.x - m0##S.x; p0  = dx * dx * __builtin_amdgcn_rcpf(v0##S.x);   \
        dx = t.y - m0##S.y; p0 += dx * dx * __builtin_amdgcn_rcpf(v0##S.y);   \
        dx = t.z - m0##S.z; p0 += dx * dx * __builtin_amdgcn_rcpf(v0##S.z);   \
        dx = t.w - m0##S.w; p0 += dx * dx * __builtin_amdgcn_rcpf(v0##S.w);   \
        p0 += __logf(v0##S.x * v0##S.y * v0##S.z * v0##S.w);                  \
        dx = t.x - m1##S.x; p1  = dx * dx * __builtin_amdgcn_rcpf(v1##S.x);   \
        dx = t.y - m1##S.y; p1 += dx * dx * __builtin_amdgcn_rcpf(v1##S.y);   \
        dx = t.z - m1##S.z; p1 += dx * dx * __builtin_amdgcn_rcpf(v1##S.z);   \
        dx = t.w - m1##S.w; p1 += dx * dx * __builtin_amdgcn_rcpf(v1##S.w);   \
        p1 += __logf(v1##S.x * v1##S.y * v1##S.z * v1##S.w);                  \
        dx = t.x - m2##S.x; p2  = dx * dx * __builtin_amdgcn_rcpf(v2##S.x);   \
        dx = t.y - m2##S.y; p2 += dx * dx * __builtin_amdgcn_rcpf(v2##S.y);   \
        dx = t.z - m2##S.z; p2 += dx * dx * __builtin_amdgcn_rcpf(v2##S.z);   \
        dx = t.w - m2##S.w; p2 += dx * dx * __builtin_amdgcn_rcpf(v2##S.w);   \
        p2 += __logf(v2##S.x * v2##S.y * v2##S.z * v2##S.w);                  \
        dx = t.x - m3##S.x; p3  = dx * dx * __builtin_amdgcn_rcpf(v3##S.x);   \
        dx = t.y - m3##S.y; p3 += dx * dx * __builtin_amdgcn_rcpf(v3##S.y);   \
        dx = t.z - m3##S.z; p3 += dx * dx * __builtin_amdgcn_rcpf(v3##S.z);   \
        dx = t.w - m3##S.w; p3 += dx * dx * __builtin_amdgcn_rcpf(v3##S.w);   \
        p3 += __logf(v3##S.x * v3##S.y * v3##S.z * v3##S.w);                  \
        p0 += __shfl_xor(p0, 1); p1 += __shfl_xor(p1, 1);                     \
        p2 += __shfl_xor(p2, 1); p3 += __shfl_xor(p3, 1);                     \
        p0 += __shfl_xor(p0, 2); p1 += __shfl_xor(p1, 2);                     \
        p2 += __shfl_xor(p2, 2); p3 += __shfl_xor(p3, 2);                     \
        p0 += __shfl_xor(p0, 4); p1 += __shfl_xor(p1, 4);                     \
        p2 += __shfl_xor(p2, 4); p3 += __shfl_xor(p3, 4);                     \
        p0 += __shfl_xor(p0, 8); p1 += __shfl_xor(p1, 8);                     \
        p2 += __shfl_xor(p2, 8); p3 += __shfl_xor(p3, 8);                     \
        const float base = -0.5f * (DIM * LOG_2PI);                           \
        float lw0 = base - 0.5f * p0;                                         \
        float lw1 = base - 0.5f * p1;                                         \
        float lw2 = base - 0.5f * p2;                                         \
        float lw3 = base - 0.5f * p3;                                         \
        lw0 = fminf(fmaxf(lw0, -100.0f), 0.0f) + __logf(w0);                  \
        lw1 = fminf(fmaxf(lw1, -100.0f), 0.0f) + __logf(w1);                  \
        lw2 = fminf(fmaxf(lw2, -100.0f), 0.0f) + __logf(w2);                  \
        lw3 = fminf(fmaxf(lw3, -100.0f), 0.0f) + __logf(w3);                  \
        float M = fmaxf(fmaxf(lw0, lw1), fmaxf(lw2, lw3));                    \
        float s = __expf(lw0 - M) + __expf(lw1 - M) +                         \
                  __expf(lw2 - M) + __expf(lw3 - M);                          \
        {                                                                     \
            const float Mo = __shfl_xor(M, 16);                               \
            const float so = __shfl_xor(s, 16);                               \
            const float Mn = fmaxf(M, Mo);                                    \
            s = s * __expf(M - Mn) + so * __expf(Mo - Mn);                    \
            M = Mn;                                                           \
        }                                                                     \
        {                                                                     \
            const float Mo = __shfl_xor(M, 32);                               \
            const float so = __shfl_xor(s, 32);                               \
            const float Mn = fmaxf(M, Mo);                                    \
            s = s * __expf(M - Mn) + so * __expf(Mo - Mn);                    \
            M = Mn;                                                           \
        }                                                                     \
        if ((bb) < B && lane == 0) out[bb] = -(M + __logf(s));                \
    }

    f32x4 m0A, m1A, m2A, m3A, v0A, v1A, v2A, v3A;
    f32x4 m0B, m1B, m2B, m3B, v0B, v1B, v2B, v3B;

    // software pipeline: next row's loads are in flight through every compute
    ISSUE(A, b0 + 0)
    ISSUE(B, b0 + 1)
    COMPUTE(A, b0 + 0)
    ISSUE(A, b0 + 2)
    COMPUTE(B, b0 + 1)
    ISSUE(B, b0 + 3)
    COMPUTE(A, b0 + 2)
    COMPUTE(B, b0 + 3)

#undef ISSUE
#undef COMPUTE
}

extern "C" void kernel_launch(void* const* d_in, const int* in_sizes, int n_in,
                              void* d_out, int out_size, void* d_ws, size_t ws_size,
                              hipStream_t stream) {
    const float* means   = (const float*)d_in[0];
    const float* covs    = (const float*)d_in[1];
    const float* weights = (const float*)d_in[2];
    const float* targets = (const float*)d_in[3];
    float* out = (float*)d_out;

    const int B = in_sizes[0] / (NG * DIM);                      // 32768
    const int grid = (B + ROWS_PER_BLOCK - 1) / ROWS_PER_BLOCK;  // 2048
    gmm_loss_kernel<<<grid, 256, 0, stream>>>(means, covs, weights, targets, out, B);
}

// Round 5
// 262.272 us; speedup vs baseline: 1.0915x; 1.0088x over previous
//
#include <hip/hip_runtime.h>
#include <math.h>

#define NG 16
#define DIM 64
#define LOG_2PI 1.8378770664093453f
#define RPW 4                      // rows per wave
#define WPB 4                      // waves per block (256 threads)
#define ROWS_PER_BLOCK (RPW * WPB) // 16

typedef float f32x4 __attribute__((ext_vector_type(4)));

// Round-4 (resubmit; round-4 bench died on GPU acquisition, no data):
// round 3 (reg double-buffered m/v pipeline + NT loads) dropped the kernel
// from 105us to <77us. Residual theory: the targets float4 + weights loads
// were issued at the TOP of each COMPUTE and consumed immediately -- a
// serial, un-hidden memory round trip inside every compute phase.
// Fix: hoist ALL rows' t/w loads into the wave prologue (4 rows/wave -> just
// 4 float4 + 4 scalars, ~20 VGPR), so every COMPUTE phase touches only
// already-resident registers. Also: load w[lane&15] once + one __logf +
// 4 shuffles instead of 4 scalar loads + 4 logs (bitwise-identical numerics).
//
// Mapping (verified, absmax=0): float4 f = lane + 64k of a row ->
// gaussian (lane>>4)+4k, dim-chunk lane&15 (same for all k). Butterfly
// 1/2/4/8 sums chunks; local 4-wide LSE; merge disjoint groups via xor 16/32.

#define NT(p) __builtin_nontemporal_load(p)

__global__ __launch_bounds__(256) void gmm_loss_kernel(
    const float* __restrict__ means,
    const float* __restrict__ covs,
    const float* __restrict__ weights,
    const float* __restrict__ targets,
    float* __restrict__ out, int B)
{
    const int lane = threadIdx.x & 63;
    const int wave = threadIdx.x >> 6;
    const int G = lane >> 4;     // lane group = base gaussian
    const int c = lane & 15;     // dim-chunk / weight index owned by this lane

    const int b0 = blockIdx.x * ROWS_PER_BLOCK + wave * RPW;

    // ---------- prologue: ALL rows' target chunks + weight scalars ----------
    // (cacheable loads: targets=8MB / weights=2MB persist in LLC across
    //  iterations; issued before any m/v load so they are resident before
    //  the first COMPUTE begins)
    const int rb0 = (b0 + 0) < B ? (b0 + 0) : (B - 1);
    const int rb1 = (b0 + 1) < B ? (b0 + 1) : (B - 1);
    const int rb2 = (b0 + 2) < B ? (b0 + 2) : (B - 1);
    const int rb3 = (b0 + 3) < B ? (b0 + 3) : (B - 1);
    const f32x4 tp0 = ((const f32x4*)(targets + (size_t)rb0 * DIM))[c];
    const f32x4 tp1 = ((const f32x4*)(targets + (size_t)rb1 * DIM))[c];
    const f32x4 tp2 = ((const f32x4*)(targets + (size_t)rb2 * DIM))[c];
    const f32x4 tp3 = ((const f32x4*)(targets + (size_t)rb3 * DIM))[c];
    const float wp0 = weights[(size_t)rb0 * NG + c];
    const float wp1 = weights[(size_t)rb1 * NG + c];
    const float wp2 = weights[(size_t)rb2 * NG + c];
    const float wp3 = weights[(size_t)rb3 * NG + c];

    // ---- issue row (bb)'s 8 big loads into buffer S (nontemporal) ----
#define ISSUE(S, bb) {                                                        \
        const int rb = (bb) < B ? (bb) : (B - 1);                             \
        const f32x4* Mp = (const f32x4*)(means + (size_t)rb * (NG * DIM));    \
        const f32x4* Vp = (const f32x4*)(covs  + (size_t)rb * (NG * DIM));    \
        m0##S = NT(Mp + lane);       v0##S = NT(Vp + lane);                   \
        m1##S = NT(Mp + lane + 64);  v1##S = NT(Vp + lane + 64);              \
        m2##S = NT(Mp + lane + 128); v2##S = NT(Vp + lane + 128);             \
        m3##S = NT(Mp + lane + 192); v3##S = NT(Vp + lane + 192);             \
    }

    // ---- consume buffer S for row (bb); t/w already in registers ----
#define COMPUTE(S, bb, t, wv) {                                               \
        float dx, p0, p1, p2, p3;                                             \
        dx = t.x - m0##S.x; p0  = dx * dx * __builtin_amdgcn_rcpf(v0##S.x);   \
        dx = t.y - m0##S.y; p0 += dx * dx * __builtin_amdgcn_rcpf(v0##S.y);   \
        dx = t.z - m0##S.z; p0 += dx * dx * __builtin_amdgcn_rcpf(v0##S.z);   \
        dx = t.w - m0##S.w; p0 += dx * dx * __builtin_amdgcn_rcpf(v0##S.w);   \
        p0 += __logf(v0##S.x * v0##S.y * v0##S.z * v0##S.w);                  \
        dx = t.x - m1##S.x; p1  = dx * dx * __builtin_amdgcn_rcpf(v1##S.x);   \
        dx = t.y - m1##S.y; p1 += dx * dx * __builtin_amdgcn_rcpf(v1##S.y);   \
        dx = t.z - m1##S.z; p1 += dx * dx * __builtin_amdgcn_rcpf(v1##S.z);   \
        dx = t.w - m1##S.w; p1 += dx * dx * __builtin_amdgcn_rcpf(v1##S.w);   \
        p1 += __logf(v1##S.x * v1##S.y * v1##S.z * v1##S.w);                  \
        dx = t.x - m2##S.x; p2  = dx * dx * __builtin_amdgcn_rcpf(v2##S.x);   \
        dx = t.y - m2##S.y; p2 += dx * dx * __builtin_amdgcn_rcpf(v2##S.y);   \
        dx = t.z - m2##S.z; p2 += dx * dx * __builtin_amdgcn_rcpf(v2##S.z);   \
        dx = t.w - m2##S.w; p2 += dx * dx * __builtin_amdgcn_rcpf(v2##S.w);   \
        p2 += __logf(v2##S.x * v2##S.y * v2##S.z * v2##S.w);                  \
        dx = t.x - m3##S.x; p3  = dx * dx * __builtin_amdgcn_rcpf(v3##S.x);   \
        dx = t.y - m3##S.y; p3 += dx * dx * __builtin_amdgcn_rcpf(v3##S.y);   \
        dx = t.z - m3##S.z; p3 += dx * dx * __builtin_amdgcn_rcpf(v3##S.z);   \
        dx = t.w - m3##S.w; p3 += dx * dx * __builtin_amdgcn_rcpf(v3##S.w);   \
        p3 += __logf(v3##S.x * v3##S.y * v3##S.z * v3##S.w);                  \
        p0 += __shfl_xor(p0, 1); p1 += __shfl_xor(p1, 1);                     \
        p2 += __shfl_xor(p2, 1); p3 += __shfl_xor(p3, 1);                     \
        p0 += __shfl_xor(p0, 2); p1 += __shfl_xor(p1, 2);                     \
        p2 += __shfl_xor(p2, 2); p3 += __shfl_xor(p3, 2);                     \
        p0 += __shfl_xor(p0, 4); p1 += __shfl_xor(p1, 4);                     \
        p2 += __shfl_xor(p2, 4); p3 += __shfl_xor(p3, 4);                     \
        p0 += __shfl_xor(p0, 8); p1 += __shfl_xor(p1, 8);                     \
        p2 += __shfl_xor(p2, 8); p3 += __shfl_xor(p3, 8);                     \
        /* log-weights: one log per lane, fan out by shuffle (lane g in    */ \
        /* 0..15 holds log(w[g]); identical input => bitwise-same result)  */ \
        const float lg = __logf(wv);                                          \
        const float lg0 = __shfl(lg, G);                                      \
        const float lg1 = __shfl(lg, G + 4);                                  \
        const float lg2 = __shfl(lg, G + 8);                                  \
        const float lg3 = __shfl(lg, G + 12);                                 \
        const float base = -0.5f * (DIM * LOG_2PI);                           \
        float lw0 = base - 0.5f * p0;                                         \
        float lw1 = base - 0.5f * p1;                                         \
        float lw2 = base - 0.5f * p2;                                         \
        float lw3 = base - 0.5f * p3;                                         \
        lw0 = fminf(fmaxf(lw0, -100.0f), 0.0f) + lg0;                         \
        lw1 = fminf(fmaxf(lw1, -100.0f), 0.0f) + lg1;                         \
        lw2 = fminf(fmaxf(lw2, -100.0f), 0.0f) + lg2;                         \
        lw3 = fminf(fmaxf(lw3, -100.0f), 0.0f) + lg3;                         \
        float M = fmaxf(fmaxf(lw0, lw1), fmaxf(lw2, lw3));                    \
        float s = __expf(lw0 - M) + __expf(lw1 - M) +                         \
                  __expf(lw2 - M) + __expf(lw3 - M);                          \
        {                                                                     \
            const float Mo = __shfl_xor(M, 16);                               \
            const float so = __shfl_xor(s, 16);                               \
            const float Mn = fmaxf(M, Mo);                                    \
            s = s * __expf(M - Mn) + so * __expf(Mo - Mn);                    \
            M = Mn;                                                           \
        }                                                                     \
        {                                                                     \
            const float Mo = __shfl_xor(M, 32);                               \
            const float so = __shfl_xor(s, 32);                               \
            const float Mn = fmaxf(M, Mo);                                    \
            s = s * __expf(M - Mn) + so * __expf(Mo - Mn);                    \
            M = Mn;                                                           \
        }                                                                     \
        if ((bb) < B && lane == 0) out[bb] = -(M + __logf(s));                \
    }

    f32x4 m0A, m1A, m2A, m3A, v0A, v1A, v2A, v3A;
    f32x4 m0B, m1B, m2B, m3B, v0B, v1B, v2B, v3B;

    // software pipeline: next row's m/v loads in flight through every compute;
    // t/w for all rows already resident from the prologue
    ISSUE(A, b0 + 0)
    ISSUE(B, b0 + 1)
    COMPUTE(A, b0 + 0, tp0, wp0)
    ISSUE(A, b0 + 2)
    COMPUTE(B, b0 + 1, tp1, wp1)
    ISSUE(B, b0 + 3)
    COMPUTE(A, b0 + 2, tp2, wp2)
    COMPUTE(B, b0 + 3, tp3, wp3)

#undef ISSUE
#undef COMPUTE
}

extern "C" void kernel_launch(void* const* d_in, const int* in_sizes, int n_in,
                              void* d_out, int out_size, void* d_ws, size_t ws_size,
                              hipStream_t stream) {
    const float* means   = (const float*)d_in[0];
    const float* covs    = (const float*)d_in[1];
    const float* weights = (const float*)d_in[2];
    const float* targets = (const float*)d_in[3];
    float* out = (float*)d_out;

    const int B = in_sizes[0] / (NG * DIM);                      // 32768
    const int grid = (B + ROWS_PER_BLOCK - 1) / ROWS_PER_BLOCK;  // 2048
    gmm_loss_kernel<<<grid, 256, 0, stream>>>(means, covs, weights, targets, out, B);
}